// Round 16
// baseline (498.650 us; speedup 1.0000x reference)
//
#include <hip/hip_runtime.h>
#include <hip/hip_bf16.h>

#define HC 256      // H*C == IN
#define DHID 1024
#define LN_EPS 1e-5f
#define NSLOT 1024  // distributed LN-stat accumulator slots (pairs of doubles)

typedef unsigned short u16;
typedef unsigned int u32;
typedef __attribute__((ext_vector_type(8))) short bf16x8;   // 8 bf16 = 4 VGPRs
typedef __attribute__((ext_vector_type(4))) float f32x4;
typedef _Float16 __attribute__((ext_vector_type(2))) h2;    // packed half pair

__device__ __forceinline__ float bf2f(u16 u) {
  union { u32 i; float f; } v; v.i = ((u32)u) << 16; return v.f;
}
__device__ __forceinline__ u16 f2bf(float f) {
  union { float f; u32 i; } v; v.f = f;
  u32 r = v.i + 0x7fffu + ((v.i >> 16) & 1u);
  return (u16)(r >> 16);
}
__device__ __forceinline__ u16 f2h(float f) {
  union { _Float16 h; u16 u; } v; v.h = (_Float16)f; return v.u;
}
__device__ __forceinline__ float dot2(h2 a, h2 b, float c) {
  return __builtin_amdgcn_fdot2(a, b, c, false);
}
__device__ __forceinline__ float fexp2(float x) {   // raw v_exp_f32: 2^x
  float r; asm("v_exp_f32 %0, %1" : "=v"(r) : "v"(x)); return r;
}
// async global->LDS 16B: per-lane global src, wave-uniform LDS base (+lane*16 in HW)
__device__ __forceinline__ void gload16(const u16* g, u16* ldsbase, int byteoff) {
  __builtin_amdgcn_global_load_lds(
      (const __attribute__((address_space(1))) void*)g,
      (__attribute__((address_space(3))) void*)((char*)ldsbase + byteoff),
      16, 0, 0);
}

// ================= MFMA GEMM: out = op(A @ B^T_rowmajor + bias) =================
// 128x128 tile, BK=64, 256 threads = 4 waves (2x2 of 64x64), DOUBLE-buffered
// 64KB LDS -> 2 blocks/CU, with COUNTED vmcnt (T4): issue stage(t+1)'s 8 loads,
// s_waitcnt vmcnt(8) waits only stage(t); t+1's loads stay in flight across the
// raw s_barrier (no __syncthreads vmcnt(0) drain -- that drain was the 10%-
// MfmaUtil stall, R13/m97 mechanism). vmcnt(0) only on final step.
// Safety: each wave's ds_reads are reg-consumed by MFMA before barrier-2
// (compiler lgkmcnt), so buf reuse next iter is safe; sched_barrier(0) per #18.
// OMODE: 0 = f32 out + LN stats, 1 = bf16 out, 2 = f16 out.
// FUSE: blocks >= gemmBlocks execute fill_csr (independent, co-resident).
// C/D map (m89): col=lane&15, row=(lane>>4)*4+reg.
template<bool RELU, int OMODE, bool FUSE>
__global__ __launch_bounds__(256, 4) void gemm_mfma(
    const u16* __restrict__ Ab, const u16* __restrict__ BT,
    const float* __restrict__ bias,
    void* __restrict__ outp, double* __restrict__ sl,
    int M, int K, int NB, int mb,
    const int* __restrict__ srcE, const int* __restrict__ dstE,
    const int* __restrict__ offc, int* __restrict__ cur,
    int* __restrict__ csr, int E, int gemmBlocks)
{
  __shared__ __align__(16) u16 Asm[2][128 * 64];   // 2 x 16 KB
  __shared__ __align__(16) u16 Bsm[2][128 * 64];   // 2 x 16 KB
  int bxl, byl;
  if (FUSE) {
    if ((int)blockIdx.x >= gemmBlocks) {        // fill_csr blocks
      int i = ((int)blockIdx.x - gemmBlocks) * 256 + threadIdx.x;
      if (i < E) {
        int d = dstE[i];
        int pos = offc[d] + atomicAdd(&cur[d], 1);
        csr[pos] = srcE[i] << 10;               // pre-shifted byte offset
      }
      return;
    }
    bxl = blockIdx.x % mb; byl = blockIdx.x / mb;
  } else {
    bxl = blockIdx.x; byl = blockIdx.y;
  }
  const int tid = threadIdx.x;
  const int wid = tid >> 6, lane = tid & 63;
  const int rowBase = bxl * 128;
  const int colBase = byl * 128;
  const int wr = (wid >> 1) * 64, wc = (wid & 1) * 64;
  const int ccol = lane & 15, g = lane >> 4;
  f32x4 acc[4][4] = {};
  const int nt = K >> 6;
  const int lbw = __builtin_amdgcn_readfirstlane(wid * 1024);

  auto stage = [&](int t, u16* Ap, u16* Bp) {
    const int k0 = t << 6;
#pragma unroll
    for (int s = 0; s < 4; ++s) {     // A 128x64 (1024 chunks / 256 thr)
      const int L = s * 256 + tid;
      const int r = L >> 3;
      const int gc = ((L & 7) ^ (r & 7)) << 3;
      int gr = rowBase + r; gr = gr < M ? gr : M - 1;
      gload16(&Ab[(size_t)gr * K + k0 + gc], Ap, s * 4096 + lbw);
    }
#pragma unroll
    for (int s = 0; s < 4; ++s) {     // B^T 128x64
      const int L = s * 256 + tid;
      const int r = L >> 3;
      const int gc = ((L & 7) ^ (r & 7)) << 3;
      gload16(&BT[(size_t)(colBase + r) * K + k0 + gc], Bp, s * 4096 + lbw);
    }
  };

  stage(0, Asm[0], Bsm[0]);
  for (int t = 0; t < nt; ++t) {
    const int cb = t & 1;
    if (t + 1 < nt) {
      stage(t + 1, Asm[cb ^ 1], Bsm[cb ^ 1]);   // 8 loads stay in flight
      asm volatile("s_waitcnt vmcnt(8)" ::: "memory");   // stage(t) done only
    } else {
      asm volatile("s_waitcnt vmcnt(0)" ::: "memory");   // final: drain
    }
    __builtin_amdgcn_sched_barrier(0);
    __builtin_amdgcn_s_barrier();               // stage(t) visible to all waves
    const u16* Ap = Asm[cb];
    const u16* Bp = Bsm[cb];
#pragma unroll
    for (int kk = 0; kk < 2; ++kk) {
      bf16x8 af[4], bfr[4];
      const int q = kk * 4 + g;
#pragma unroll
      for (int mr = 0; mr < 4; ++mr) {
        const int row = wr + mr * 16 + ccol;
        af[mr] = *(const bf16x8*)&Ap[(row << 6) + ((q ^ (row & 7)) << 3)];
      }
#pragma unroll
      for (int nc = 0; nc < 4; ++nc) {
        const int row = wc + nc * 16 + ccol;
        bfr[nc] = *(const bf16x8*)&Bp[(row << 6) + ((q ^ (row & 7)) << 3)];
      }
#pragma unroll
      for (int mr = 0; mr < 4; ++mr)
#pragma unroll
        for (int nc = 0; nc < 4; ++nc)
          acc[mr][nc] = __builtin_amdgcn_mfma_f32_16x16x32_bf16(af[mr], bfr[nc], acc[mr][nc], 0, 0, 0);
    }
    __builtin_amdgcn_s_barrier();               // all reads of buf[cb] done
  }

  // ---- epilogue ----
  u16* ob = (u16*)outp;
  float* of = (float*)outp;
  const int crow = g * 4;
  float s1 = 0.f, s2 = 0.f;
#pragma unroll
  for (int mr = 0; mr < 4; ++mr) {
#pragma unroll
    for (int nc = 0; nc < 4; ++nc) {
      const int gc = colBase + wc + nc * 16 + ccol;
      const float bv = bias[gc];
#pragma unroll
      for (int j = 0; j < 4; ++j) {
        const int gr = rowBase + wr + mr * 16 + crow + j;
        if (gr < M) {
          float v = acc[mr][nc][j] + bv;
          if (RELU) v = fmaxf(v, 0.f);
          if (OMODE == 1) {
            ob[(size_t)gr * NB + gc] = f2bf(v);
          } else if (OMODE == 2) {
            ob[(size_t)gr * NB + gc] = f2h(v);
          } else {
            of[(size_t)gr * NB + gc] = v;
            s1 += v; s2 += v * v;
          }
        }
      }
    }
  }
  if (OMODE == 0) {
#pragma unroll
    for (int d = 1; d < 64; d <<= 1) {
      s1 += __shfl_xor(s1, d);
      s2 += __shfl_xor(s2, d);
    }
    if (lane == 0) {
      int slot = ((bxl + byl * 397) * 4 + wid) & (NSLOT - 1);
      atomicAdd(&sl[slot * 2 + 0], (double)s1);
      atomicAdd(&sl[slot * 2 + 1], (double)s2);
    }
  }
}

// ============ merged pre-stage: xcvt | transpose_all | deg_count ============
__global__ __launch_bounds__(256) void pre_stage(
    const float* __restrict__ x, u16* __restrict__ xb, long n8,
    const float* __restrict__ Wl, const float* __restrict__ Wr,
    const float* __restrict__ W2, const float* __restrict__ W3,
    u16* __restrict__ WT1, u16* __restrict__ W2T, u16* __restrict__ W3T,
    const int* __restrict__ dst, int* __restrict__ deg, int E)
{
  __shared__ float T[32][33];
  const int bx = blockIdx.x;
  if (bx < 2048) {
    for (long i = (long)bx * 256 + threadIdx.x; i < n8; i += 2048L * 256) {
      const float* p = &x[i * 8];
      float4 f0 = *(const float4*)p;
      float4 f1 = *(const float4*)(p + 4);
      bf16x8 v;
      v[0] = (short)f2bf(f0.x); v[1] = (short)f2bf(f0.y);
      v[2] = (short)f2bf(f0.z); v[3] = (short)f2bf(f0.w);
      v[4] = (short)f2bf(f1.x); v[5] = (short)f2bf(f1.y);
      v[6] = (short)f2bf(f1.z); v[7] = (short)f2bf(f1.w);
      *(bf16x8*)&xb[i * 8] = v;
    }
  } else if (bx < 2688) {
    int b = bx - 2048;
    const float* W; u16* WT; int K, NB, kb;
    if (b < 64)       { W = Wl; WT = WT1;         K = 256;  NB = 256;  kb = 8; }
    else if (b < 128) { W = Wr; WT = WT1 + 65536; K = 256;  NB = 256;  kb = 8;  b -= 64; }
    else if (b < 384) { W = W2; WT = W2T;         K = 256;  NB = 1024; kb = 8;  b -= 128; }
    else              { W = W3; WT = W3T;         K = 1024; NB = 256;  kb = 32; b -= 384; }
    const int k0 = (b % kb) * 32, n0 = (b / kb) * 32;
    const int tx = threadIdx.x & 31, ty = threadIdx.x >> 5;   // 32 x 8
#pragma unroll
    for (int i = 0; i < 32; i += 8)
      T[ty + i][tx] = W[(size_t)(k0 + ty + i) * NB + n0 + tx];
    __syncthreads();
#pragma unroll
    for (int i = 0; i < 32; i += 8)
      WT[(size_t)(n0 + ty + i) * K + k0 + tx] = f2bf(T[tx][ty + i]);
  } else {
    int i = (bx - 2688) * 256 + threadIdx.x;
    if (i < E) atomicAdd(&deg[dst[i]], 1);
  }
}

// ---------------- CSR build: run-per-thread exclusive scan ----------------
__global__ __launch_bounds__(1024) void scan_k(const int* __restrict__ deg, int* __restrict__ off, int n) {
  __shared__ int wsum[16];
  const int tid = threadIdx.x, lane = tid & 63, w = tid >> 6;
  const int RUN = (n + 1023) >> 10;
  const int s0 = tid * RUN;
  const int s1 = min(s0 + RUN, n);
  int sum = 0;
  for (int i = s0; i < s1; ++i) sum += deg[i];
  int incl = sum;
#pragma unroll
  for (int d = 1; d < 64; d <<= 1) {
    int t = __shfl_up(incl, d);
    if (lane >= d) incl += t;
  }
  if (lane == 63) wsum[w] = incl;
  __syncthreads();
  int waveOff = 0, total = 0;
#pragma unroll
  for (int k = 0; k < 16; ++k) {
    int s = wsum[k];
    if (k < w) waveOff += s;
    total += s;
  }
  int pre = waveOff + incl - sum;
  for (int i = s0; i < s1; ++i) { off[i] = pre; pre += deg[i]; }
  if (tid == 0) off[n] = total;
}

// ---------------- fused GATv2 edge-softmax-aggregate: one wave per node ----------------
// xlr f16 [N][512] (xl | xr). att pre-scaled by log2e -> p = v_exp_f32(part - m0).
// csr entries are pre-shifted byte offsets. 8-edge chunks. Residual from xb (bf16).
__global__ __launch_bounds__(256) void gat_agg(
    const u16* __restrict__ xlr, const u16* __restrict__ xb,
    const int* __restrict__ off, const int* __restrict__ csr,
    const float* __restrict__ att, const float* __restrict__ b_gat,
    u16* __restrict__ ybf, double* __restrict__ sl, int N)
{
  const int lane = threadIdx.x & 63;
  const int node = blockIdx.x * 4 + (threadIdx.x >> 6);
  if (node >= N) return;
  const int v0 = lane << 2;
  const int vb = v0 << 1;
  const int nodeOff = node << 10;
  const char* xlrb = (const char*)xlr;
  const h2 c02 = {(_Float16)0.2f, (_Float16)0.2f};
  h2 att01, att23;
  {
    const float L2E = 1.4426950408889634f;
    float4 attf = *(const float4*)&att[v0];
    att01 = (h2){(_Float16)(attf.x * L2E), (_Float16)(attf.y * L2E)};
    att23 = (h2){(_Float16)(attf.z * L2E), (_Float16)(attf.w * L2E)};
  }
  h2 xr01, xr23;
  {
    uint2 ux = *(const uint2*)(xlrb + nodeOff + 512 + vb);
    xr01 = __builtin_bit_cast(h2, ux.x);
    xr23 = __builtin_bit_cast(h2, ux.y);
  }
  // self-loop: reference logit m0 (log2 domain), p_self = 1
  float m0, d_run = 1.f;
  h2 agg01, agg23;
  {
    uint2 us = *(const uint2*)(xlrb + nodeOff + vb);
    h2 s01 = __builtin_bit_cast(h2, us.x);
    h2 s23 = __builtin_bit_cast(h2, us.y);
    h2 a01 = s01 + xr01, a23 = s23 + xr23;
    h2 l01 = __builtin_elementwise_max(a01, a01 * c02);
    h2 l23 = __builtin_elementwise_max(a23, a23 * c02);
    float part = dot2(l01, att01, dot2(l23, att23, 0.f));
    part += __shfl_xor(part, 1);
    part += __shfl_xor(part, 2);
    part += __shfl_xor(part, 4);
    m0 = part;
    agg01 = s01; agg23 = s23;
  }
  const int beg = off[node];
  const int cntE = off[node + 1] - beg;
  for (int e0 = 0; e0 < cntE; e0 += 8) {
    const int nb = cntE - e0;   // valid this chunk: min(nb, 8)
    int jj[8];
#pragma unroll
    for (int t = 0; t < 8; ++t)
      jj[t] = (t < nb) ? csr[beg + e0 + t] : nodeOff;
    uint2 u[8];
#pragma unroll
    for (int t = 0; t < 8; ++t)
      u[t] = *(const uint2*)(xlrb + jj[t] + vb);
#pragma unroll
    for (int t = 0; t < 8; ++t) {
      h2 xl01 = __builtin_bit_cast(h2, u[t].x);
      h2 xl23 = __builtin_bit_cast(h2, u[t].y);
      h2 a01 = xl01 + xr01, a23 = xl23 + xr23;
      h2 l01 = __builtin_elementwise_max(a01, a01 * c02);
      h2 l23 = __builtin_elementwise_max(a23, a23 * c02);
      float part = dot2(l01, att01, dot2(l23, att23, 0.f));
      part += __shfl_xor(part, 1);
      part += __shfl_xor(part, 2);
      part += __shfl_xor(part, 4);
      float p = (t < nb) ? fexp2(part - m0) : 0.f;
      d_run += p;
      _Float16 ph = (_Float16)p;
      h2 pv = {ph, ph};
      agg01 += pv * xl01;    // v_pk_fma_f16
      agg23 += pv * xl23;
    }
  }
  const float inv = 1.f / d_run;
  float xv[4];
  {
    ushort4 ux = *(const ushort4*)&xb[(size_t)node * HC + v0];
    xv[0] = bf2f(ux.x); xv[1] = bf2f(ux.y); xv[2] = bf2f(ux.z); xv[3] = bf2f(ux.w);
  }
  float bg[4];
  *(float4*)bg = *(const float4*)&b_gat[v0];
  float s1, s2;
  ushort4 ov;
  {
    float v0f = fmaf((float)agg01.x, inv, bg[0]) + xv[0];
    float v1f = fmaf((float)agg01.y, inv, bg[1]) + xv[1];
    float v2f = fmaf((float)agg23.x, inv, bg[2]) + xv[2];
    float v3f = fmaf((float)agg23.y, inv, bg[3]) + xv[3];
    s1 = v0f + v1f + v2f + v3f;
    s2 = v0f * v0f + v1f * v1f + v2f * v2f + v3f * v3f;
    ov.x = f2bf(v0f); ov.y = f2bf(v1f); ov.z = f2bf(v2f); ov.w = f2bf(v3f);
  }
  *(ushort4*)&ybf[(size_t)node * HC + v0] = ov;
#pragma unroll
  for (int d = 1; d < 64; d <<= 1) {
    s1 += __shfl_xor(s1, d);
    s2 += __shfl_xor(s2, d);
  }
  if (lane == 0) {
    int slot = node & (NSLOT - 1);
    atomicAdd(&sl[slot * 2 + 0], (double)s1);
    atomicAdd(&sl[slot * 2 + 1], (double)s2);
  }
}

// ============ merged LN1-finalize + W2T scale + bias fold ============
__global__ __launch_bounds__(256) void w2fold(
    const double* __restrict__ sl, const float* __restrict__ g1,
    const float* __restrict__ be1, u16* __restrict__ W2T,
    const float* __restrict__ b2, const float* __restrict__ W2,
    float* __restrict__ bias2p, double cnt)
{
  __shared__ double red[256][2];
  const int tid = threadIdx.x;
  double s1 = 0.0, s2 = 0.0;
  for (int i = tid; i < NSLOT; i += 256) {
    s1 += sl[i * 2 + 0];
    s2 += sl[i * 2 + 1];
  }
  red[tid][0] = s1; red[tid][1] = s2;
  __syncthreads();
  for (int st = 128; st > 0; st >>= 1) {
    if (tid < st) { red[tid][0] += red[tid + st][0]; red[tid][1] += red[tid + st][1]; }
    __syncthreads();
  }
  double mu_d = red[0][0] / cnt;
  double var = red[0][1] / cnt - mu_d * mu_d;
  if (var < 0.0) var = 0.0;
  const float sc = (float)(1.0 / (sqrt(var) + (double)LN_EPS));
  const float mu = (float)mu_d;
  const int bx = blockIdx.x;
  if (bx < 128) {
    const int i = bx * 256 + tid;
    const int kb = (i & 31) << 3;
    bf16x8 v = *(bf16x8*)&W2T[(size_t)i * 8];
    bf16x8 w;
#pragma unroll
    for (int j = 0; j < 8; ++j)
      w[j] = (short)f2bf(bf2f((u16)v[j]) * (sc * g1[kb + j]));
    *(bf16x8*)&W2T[(size_t)i * 8] = w;
  } else {
    const int n = (bx - 128) * 256 + tid;
    if (n < DHID) {
      float s = b2[n];
      for (int k = 0; k < HC; ++k) {
        float B1k = be1[k] - mu * sc * g1[k];
        s = fmaf(B1k, W2[(size_t)k * DHID + n], s);
      }
      bias2p[n] = s;
    }
  }
}

// ============ merged LN3-finalize + apply in place on d_out ============
__global__ __launch_bounds__(256) void ln_apply(
    const double* __restrict__ sl, const float* __restrict__ g3,
    const float* __restrict__ be3, float* __restrict__ z,
    long total4, double cnt)
{
  __shared__ double red[256][2];
  const int tid = threadIdx.x;
  double s1 = 0.0, s2 = 0.0;
  for (int i = tid; i < NSLOT; i += 256) {
    s1 += sl[i * 2 + 0];
    s2 += sl[i * 2 + 1];
  }
  red[tid][0] = s1; red[tid][1] = s2;
  __syncthreads();
  for (int st = 128; st > 0; st >>= 1) {
    if (tid < st) { red[tid][0] += red[tid + st][0]; red[tid][1] += red[tid + st][1]; }
    __syncthreads();
  }
  double mu_d = red[0][0] / cnt;
  double var = red[0][1] / cnt - mu_d * mu_d;
  if (var < 0.0) var = 0.0;
  const float sc = (float)(1.0 / (sqrt(var) + (double)LN_EPS));
  const float mu = (float)mu_d;
  for (long i = blockIdx.x * (long)blockDim.x + tid; i < total4;
       i += (long)gridDim.x * blockDim.x) {
    int c0 = (int)((i << 2) & (HC - 1));
    float4 v = ((float4*)z)[i];
    float4 gv = *(const float4*)&g3[c0];
    float4 bv = *(const float4*)&be3[c0];
    v.x = fmaf(v.x - mu, sc * gv.x, bv.x);
    v.y = fmaf(v.y - mu, sc * gv.y, bv.y);
    v.z = fmaf(v.z - mu, sc * gv.z, bv.z);
    v.w = fmaf(v.w - mu, sc * gv.w, bv.w);
    ((float4*)z)[i] = v;
  }
}

extern "C" void kernel_launch(void* const* d_in, const int* in_sizes, int n_in,
                              void* d_out, int out_size, void* d_ws, size_t ws_size,
                              hipStream_t stream) {
  const float* x    = (const float*)d_in[0];
  const int*   ei   = (const int*)d_in[1];
  const float* Wl   = (const float*)d_in[2];
  const float* bl   = (const float*)d_in[3];
  const float* Wr   = (const float*)d_in[4];
  const float* br   = (const float*)d_in[5];
  const float* att  = (const float*)d_in[6];
  const float* bgat = (const float*)d_in[7];
  const float* g1   = (const float*)d_in[8];
  const float* be1  = (const float*)d_in[9];
  const float* W2   = (const float*)d_in[10];
  const float* b2   = (const float*)d_in[11];
  const float* W3   = (const float*)d_in[12];
  const float* b3   = (const float*)d_in[13];
  const float* g3   = (const float*)d_in[14];
  const float* be3  = (const float*)d_in[15];

  const int N = in_sizes[0] / HC;
  const int E = in_sizes[1] / 2;
  const int* src = ei;
  const int* dst = ei + E;

  char* ws = (char*)d_ws;
  size_t o = 0;
  double* sl1 = (double*)(ws + o); o += (size_t)NSLOT * 16;
  double* sl3 = (double*)(ws + o); o += (size_t)NSLOT * 16;
  float* biascat = (float*)(ws + o); o += 512 * 4;
  float* bias2p = (float*)(ws + o); o += DHID * 4;
  u16* WT1 = (u16*)(ws + o); o += (size_t)512 * HC * 2;        // [WlT;WrT]: [512][256]
  u16* W2T = (u16*)(ws + o); o += (size_t)DHID * HC * 2;       // [1024][256]
  u16* W3T = (u16*)(ws + o); o += (size_t)HC * DHID * 2;       // [256][1024]
  int* deg = (int*)(ws + o); o += (size_t)N * 4;
  int* cur = (int*)(ws + o); o += (size_t)N * 4;               // contiguous with deg
  int* off = (int*)(ws + o); o += (size_t)(N + 1) * 4; o = (o + 15) & ~(size_t)15;
  int* csr = (int*)(ws + o); o += (size_t)E * 4; o = (o + 15) & ~(size_t)15;
  u16* xlr = (u16*)(ws + o); o += (size_t)N * 512 * 2;         // [N][512] f16 = xl | xr
  u16* h2m = (u16*)(ws + o); o += (size_t)N * DHID * 2;

  u16* ybf = (u16*)d_out;                     // y bf16: first half of d_out
  u16* xb  = (u16*)d_out + (size_t)N * HC;    // x bf16: second half of d_out
  float* z = (float*)d_out;                   // GEMM3's z overwrites everything later

  hipMemsetAsync(sl1, 0, (size_t)NSLOT * 32, stream);          // sl1 + sl3
  hipMemsetAsync(deg, 0, (size_t)N * 8, stream);               // deg + cur
  hipMemcpyAsync(biascat, bl, 256 * 4, hipMemcpyDeviceToDevice, stream);
  hipMemcpyAsync(biascat + 256, br, 256 * 4, hipMemcpyDeviceToDevice, stream);

  dim3 blk(256);
  const int mb = (N + 127) / 128;
  const int degBlocks = (E + 255) / 256;
  const int fillBlocks = (E + 255) / 256;
  const int g1Blocks = mb * 4;                 // GEMM1 grid (mb x 4 flattened)

  // merged pre-stage: xcvt (2048) | weight transposes (640) | deg_count
  pre_stage<<<2688 + degBlocks, blk, 0, stream>>>(
      x, xb, (long)N * HC / 8, Wl, Wr, W2, W3, WT1, W2T, W3T, dst, deg, E);

  scan_k<<<1, 1024, 0, stream>>>(deg, off, N);

  // GEMM1 (xlr = xb @ [Wl|Wr] + [bl|br], f16 out) fused with fill_csr
  gemm_mfma<false, 2, true><<<g1Blocks + fillBlocks, blk, 0, stream>>>(
      xb, WT1, biascat, xlr, nullptr, N, HC, 512, mb,
      src, dst, off, cur, csr, E, g1Blocks);

  // fused GATv2 + residual + LN1 partial stats
  gat_agg<<<(N + 3) / 4, blk, 0, stream>>>(xlr, xb, off, csr, att, bgat, ybf, sl1, N);

  // merged: LN1 finalize + W2T row-scale + bias2' fold
  w2fold<<<132, blk, 0, stream>>>(sl1, g1, be1, W2T, b2, W2, bias2p, (double)N * HC);

  // GEMM2: h2 = relu(ybf @ W2T' + bias2')  (bf16 out [N][1024])
  gemm_mfma<true, 1, false><<<dim3(mb, 8), blk, 0, stream>>>(
      ybf, W2T, bias2p, h2m, nullptr, N, HC, DHID, mb,
      nullptr, nullptr, nullptr, nullptr, nullptr, 0, 0);

  // GEMM3: z = h2 @ W3 + b3  (f32 out to d_out) + LN3 partial stats
  gemm_mfma<false, 0, false><<<dim3(mb, 2), blk, 0, stream>>>(
      h2m, W3T, b3, z, sl3, N, DHID, HC, mb,
      nullptr, nullptr, nullptr, nullptr, nullptr, 0, 0);

  // merged: LN3 finalize + apply in place
  ln_apply<<<2048, blk, 0, stream>>>(sl3, g3, be3, z, (long)N * HC / 4, (double)N * HC);
}

// Round 17
// 447.437 us; speedup vs baseline: 1.1145x; 1.1145x over previous
//
#include <hip/hip_runtime.h>
#include <hip/hip_bf16.h>

#define HC 256      // H*C == IN
#define DHID 1024
#define LN_EPS 1e-5f
#define NSLOT 1024  // distributed LN-stat accumulator slots (pairs of doubles)

typedef unsigned short u16;
typedef unsigned int u32;
typedef __attribute__((ext_vector_type(8))) short bf16x8;   // 8 bf16 = 4 VGPRs
typedef __attribute__((ext_vector_type(4))) float f32x4;
typedef _Float16 __attribute__((ext_vector_type(2))) h2;    // packed half pair

__device__ __forceinline__ float bf2f(u16 u) {
  union { u32 i; float f; } v; v.i = ((u32)u) << 16; return v.f;
}
__device__ __forceinline__ u16 f2bf(float f) {
  union { float f; u32 i; } v; v.f = f;
  u32 r = v.i + 0x7fffu + ((v.i >> 16) & 1u);
  return (u16)(r >> 16);
}
__device__ __forceinline__ u16 f2h(float f) {
  union { _Float16 h; u16 u; } v; v.h = (_Float16)f; return v.u;
}
__device__ __forceinline__ float dot2(h2 a, h2 b, float c) {
  return __builtin_amdgcn_fdot2(a, b, c, false);
}
__device__ __forceinline__ float fexp2(float x) {   // raw v_exp_f32: 2^x
  float r; asm("v_exp_f32 %0, %1" : "=v"(r) : "v"(x)); return r;
}
// async global->LDS 16B: per-lane global src, wave-uniform LDS base (+lane*16 in HW)
__device__ __forceinline__ void gload16(const u16* g, u16* ldsbase, int byteoff) {
  __builtin_amdgcn_global_load_lds(
      (const __attribute__((address_space(1))) void*)g,
      (__attribute__((address_space(3))) void*)((char*)ldsbase + byteoff),
      16, 0, 0);
}

// ================= MFMA GEMM: out = op(A @ B^T_rowmajor + bias) =================
// BM=256 x BN=128 tile, BK=64, 512 threads = 8 waves (4 row x 2 col of 64x64).
// SINGLE-buffered 48KB LDS, launch_bounds(512,4) (R14-proven best config).
// Pipelining attempts REGRESSED 3x: R13 (96KB dbuf, 1 blk/CU, -25%), R15
// (64KB dbuf + counted vmcnt, occ 19.5%, -25%): at small K (nt=4..16),
// occupancy-TLP beats source-level pipeline depth on this problem.
// XOR-16B swizzle, linear LDS, gload_lds staging (R4/R5/R9/R10-verified).
// OMODE: 0 = f32 out + LN stats, 1 = bf16 out, 2 = f16 out.
// FUSE: blocks >= gemmBlocks execute fill_csr (independent, co-resident).
// C/D map (m89): col=lane&15, row=(lane>>4)*4+reg.
template<bool RELU, int OMODE, bool FUSE>
__global__ __launch_bounds__(512, 4) void gemm_mfma(
    const u16* __restrict__ Ab, const u16* __restrict__ BT,
    const float* __restrict__ bias,
    void* __restrict__ outp, double* __restrict__ sl,
    int M, int K, int NB, int mb,
    const int* __restrict__ srcE, const int* __restrict__ dstE,
    const int* __restrict__ offc, int* __restrict__ cur,
    int* __restrict__ csr, int E, int gemmBlocks)
{
  __shared__ __align__(16) u16 Asm[256 * 64];   // 32 KB
  __shared__ __align__(16) u16 Bsm[128 * 64];   // 16 KB
  int bxl, byl;
  if (FUSE) {
    if ((int)blockIdx.x >= gemmBlocks) {        // fill_csr blocks
      int i = ((int)blockIdx.x - gemmBlocks) * 512 + threadIdx.x;
      if (i < E) {
        int d = dstE[i];
        int pos = offc[d] + atomicAdd(&cur[d], 1);
        csr[pos] = srcE[i] << 10;               // pre-shifted byte offset
      }
      return;
    }
    bxl = blockIdx.x % mb; byl = blockIdx.x / mb;
  } else {
    bxl = blockIdx.x; byl = blockIdx.y;
  }
  const int tid = threadIdx.x;
  const int wid = tid >> 6, lane = tid & 63;
  const int rowBase = bxl * 256;
  const int colBase = byl * 128;
  const int wr = (wid >> 1) * 64, wc = (wid & 1) * 64;
  const int ccol = lane & 15, g = lane >> 4;
  f32x4 acc[4][4] = {};
  const int nt = K >> 6;

  for (int t = 0; t < nt; ++t) {
    const int k0 = t << 6;
#pragma unroll
    for (int s = 0; s < 4; ++s) {     // A 256x64 (2048 chunks / 512 thr)
      const int L = s * 512 + tid;
      const int r = L >> 3;
      const int gc = ((L & 7) ^ (r & 7)) << 3;
      int gr = rowBase + r; gr = gr < M ? gr : M - 1;
      const int lb = __builtin_amdgcn_readfirstlane(s * 8192 + wid * 1024);
      gload16(&Ab[(size_t)gr * K + k0 + gc], Asm, lb);
    }
#pragma unroll
    for (int s = 0; s < 2; ++s) {     // B^T 128x64
      const int L = s * 512 + tid;
      const int r = L >> 3;
      const int gc = ((L & 7) ^ (r & 7)) << 3;
      const int lb = __builtin_amdgcn_readfirstlane(s * 8192 + wid * 1024);
      gload16(&BT[(size_t)(colBase + r) * K + k0 + gc], Bsm, lb);
    }
    __syncthreads();
#pragma unroll
    for (int kk = 0; kk < 2; ++kk) {
      bf16x8 af[4], bfr[4];
      const int q = kk * 4 + g;
#pragma unroll
      for (int mr = 0; mr < 4; ++mr) {
        const int row = wr + mr * 16 + ccol;
        af[mr] = *(const bf16x8*)&Asm[(row << 6) + ((q ^ (row & 7)) << 3)];
      }
#pragma unroll
      for (int nc = 0; nc < 4; ++nc) {
        const int row = wc + nc * 16 + ccol;
        bfr[nc] = *(const bf16x8*)&Bsm[(row << 6) + ((q ^ (row & 7)) << 3)];
      }
#pragma unroll
      for (int mr = 0; mr < 4; ++mr)
#pragma unroll
        for (int nc = 0; nc < 4; ++nc)
          acc[mr][nc] = __builtin_amdgcn_mfma_f32_16x16x32_bf16(af[mr], bfr[nc], acc[mr][nc], 0, 0, 0);
    }
    __syncthreads();
  }

  // ---- epilogue ----
  u16* ob = (u16*)outp;
  float* of = (float*)outp;
  const int crow = g * 4;
  float s1 = 0.f, s2 = 0.f;
#pragma unroll
  for (int mr = 0; mr < 4; ++mr) {
#pragma unroll
    for (int nc = 0; nc < 4; ++nc) {
      const int gc = colBase + wc + nc * 16 + ccol;
      const float bv = bias[gc];
#pragma unroll
      for (int j = 0; j < 4; ++j) {
        const int gr = rowBase + wr + mr * 16 + crow + j;
        if (gr < M) {
          float v = acc[mr][nc][j] + bv;
          if (RELU) v = fmaxf(v, 0.f);
          if (OMODE == 1) {
            ob[(size_t)gr * NB + gc] = f2bf(v);
          } else if (OMODE == 2) {
            ob[(size_t)gr * NB + gc] = f2h(v);
          } else {
            of[(size_t)gr * NB + gc] = v;
            s1 += v; s2 += v * v;
          }
        }
      }
    }
  }
  if (OMODE == 0) {
#pragma unroll
    for (int d = 1; d < 64; d <<= 1) {
      s1 += __shfl_xor(s1, d);
      s2 += __shfl_xor(s2, d);
    }
    if (lane == 0) {
      int slot = ((bxl + byl * 397) * 8 + wid) & (NSLOT - 1);
      atomicAdd(&sl[slot * 2 + 0], (double)s1);
      atomicAdd(&sl[slot * 2 + 1], (double)s2);
    }
  }
}

// ============ merged pre-stage: xcvt | transpose_all | deg_count ============
__global__ __launch_bounds__(256) void pre_stage(
    const float* __restrict__ x, u16* __restrict__ xb, long n8,
    const float* __restrict__ Wl, const float* __restrict__ Wr,
    const float* __restrict__ W2, const float* __restrict__ W3,
    u16* __restrict__ WT1, u16* __restrict__ W2T, u16* __restrict__ W3T,
    const int* __restrict__ dst, int* __restrict__ deg, int E)
{
  __shared__ float T[32][33];
  const int bx = blockIdx.x;
  if (bx < 2048) {
    for (long i = (long)bx * 256 + threadIdx.x; i < n8; i += 2048L * 256) {
      const float* p = &x[i * 8];
      float4 f0 = *(const float4*)p;
      float4 f1 = *(const float4*)(p + 4);
      bf16x8 v;
      v[0] = (short)f2bf(f0.x); v[1] = (short)f2bf(f0.y);
      v[2] = (short)f2bf(f0.z); v[3] = (short)f2bf(f0.w);
      v[4] = (short)f2bf(f1.x); v[5] = (short)f2bf(f1.y);
      v[6] = (short)f2bf(f1.z); v[7] = (short)f2bf(f1.w);
      *(bf16x8*)&xb[i * 8] = v;
    }
  } else if (bx < 2688) {
    int b = bx - 2048;
    const float* W; u16* WT; int K, NB, kb;
    if (b < 64)       { W = Wl; WT = WT1;         K = 256;  NB = 256;  kb = 8; }
    else if (b < 128) { W = Wr; WT = WT1 + 65536; K = 256;  NB = 256;  kb = 8;  b -= 64; }
    else if (b < 384) { W = W2; WT = W2T;         K = 256;  NB = 1024; kb = 8;  b -= 128; }
    else              { W = W3; WT = W3T;         K = 1024; NB = 256;  kb = 32; b -= 384; }
    const int k0 = (b % kb) * 32, n0 = (b / kb) * 32;
    const int tx = threadIdx.x & 31, ty = threadIdx.x >> 5;   // 32 x 8
#pragma unroll
    for (int i = 0; i < 32; i += 8)
      T[ty + i][tx] = W[(size_t)(k0 + ty + i) * NB + n0 + tx];
    __syncthreads();
#pragma unroll
    for (int i = 0; i < 32; i += 8)
      WT[(size_t)(n0 + ty + i) * K + k0 + tx] = f2bf(T[tx][ty + i]);
  } else {
    int i = (bx - 2688) * 256 + threadIdx.x;
    if (i < E) atomicAdd(&deg[dst[i]], 1);
  }
}

// ---------------- CSR build: run-per-thread exclusive scan ----------------
__global__ __launch_bounds__(1024) void scan_k(const int* __restrict__ deg, int* __restrict__ off, int n) {
  __shared__ int wsum[16];
  const int tid = threadIdx.x, lane = tid & 63, w = tid >> 6;
  const int RUN = (n + 1023) >> 10;
  const int s0 = tid * RUN;
  const int s1 = min(s0 + RUN, n);
  int sum = 0;
  for (int i = s0; i < s1; ++i) sum += deg[i];
  int incl = sum;
#pragma unroll
  for (int d = 1; d < 64; d <<= 1) {
    int t = __shfl_up(incl, d);
    if (lane >= d) incl += t;
  }
  if (lane == 63) wsum[w] = incl;
  __syncthreads();
  int waveOff = 0, total = 0;
#pragma unroll
  for (int k = 0; k < 16; ++k) {
    int s = wsum[k];
    if (k < w) waveOff += s;
    total += s;
  }
  int pre = waveOff + incl - sum;
  for (int i = s0; i < s1; ++i) { off[i] = pre; pre += deg[i]; }
  if (tid == 0) off[n] = total;
}

// ---------------- fused GATv2 edge-softmax-aggregate: one wave per node ----------------
// xlr f16 [N][512] (xl | xr). att pre-scaled by log2e -> p = v_exp_f32(part - m0).
// csr entries are pre-shifted byte offsets. 8-edge chunks (16 regressed: padding
// waste at avg degree ~16). Residual from xb (bf16): -19 MB HBM.
__global__ __launch_bounds__(256) void gat_agg(
    const u16* __restrict__ xlr, const u16* __restrict__ xb,
    const int* __restrict__ off, const int* __restrict__ csr,
    const float* __restrict__ att, const float* __restrict__ b_gat,
    u16* __restrict__ ybf, double* __restrict__ sl, int N)
{
  const int lane = threadIdx.x & 63;
  const int node = blockIdx.x * 4 + (threadIdx.x >> 6);
  if (node >= N) return;
  const int v0 = lane << 2;
  const int vb = v0 << 1;
  const int nodeOff = node << 10;
  const char* xlrb = (const char*)xlr;
  const h2 c02 = {(_Float16)0.2f, (_Float16)0.2f};
  h2 att01, att23;
  {
    const float L2E = 1.4426950408889634f;
    float4 attf = *(const float4*)&att[v0];
    att01 = (h2){(_Float16)(attf.x * L2E), (_Float16)(attf.y * L2E)};
    att23 = (h2){(_Float16)(attf.z * L2E), (_Float16)(attf.w * L2E)};
  }
  h2 xr01, xr23;
  {
    uint2 ux = *(const uint2*)(xlrb + nodeOff + 512 + vb);
    xr01 = __builtin_bit_cast(h2, ux.x);
    xr23 = __builtin_bit_cast(h2, ux.y);
  }
  // self-loop: reference logit m0 (log2 domain), p_self = 1
  float m0, d_run = 1.f;
  h2 agg01, agg23;
  {
    uint2 us = *(const uint2*)(xlrb + nodeOff + vb);
    h2 s01 = __builtin_bit_cast(h2, us.x);
    h2 s23 = __builtin_bit_cast(h2, us.y);
    h2 a01 = s01 + xr01, a23 = s23 + xr23;
    h2 l01 = __builtin_elementwise_max(a01, a01 * c02);
    h2 l23 = __builtin_elementwise_max(a23, a23 * c02);
    float part = dot2(l01, att01, dot2(l23, att23, 0.f));
    part += __shfl_xor(part, 1);
    part += __shfl_xor(part, 2);
    part += __shfl_xor(part, 4);
    m0 = part;
    agg01 = s01; agg23 = s23;
  }
  const int beg = off[node];
  const int cntE = off[node + 1] - beg;
  for (int e0 = 0; e0 < cntE; e0 += 8) {
    const int nb = cntE - e0;   // valid this chunk: min(nb, 8)
    int jj[8];
#pragma unroll
    for (int t = 0; t < 8; ++t)
      jj[t] = (t < nb) ? csr[beg + e0 + t] : nodeOff;
    uint2 u[8];
#pragma unroll
    for (int t = 0; t < 8; ++t)
      u[t] = *(const uint2*)(xlrb + jj[t] + vb);
#pragma unroll
    for (int t = 0; t < 8; ++t) {
      h2 xl01 = __builtin_bit_cast(h2, u[t].x);
      h2 xl23 = __builtin_bit_cast(h2, u[t].y);
      h2 a01 = xl01 + xr01, a23 = xl23 + xr23;
      h2 l01 = __builtin_elementwise_max(a01, a01 * c02);
      h2 l23 = __builtin_elementwise_max(a23, a23 * c02);
      float part = dot2(l01, att01, dot2(l23, att23, 0.f));
      part += __shfl_xor(part, 1);
      part += __shfl_xor(part, 2);
      part += __shfl_xor(part, 4);
      float p = (t < nb) ? fexp2(part - m0) : 0.f;
      d_run += p;
      _Float16 ph = (_Float16)p;
      h2 pv = {ph, ph};
      agg01 += pv * xl01;    // v_pk_fma_f16
      agg23 += pv * xl23;
    }
  }
  const float inv = 1.f / d_run;
  float xv[4];
  {
    ushort4 ux = *(const ushort4*)&xb[(size_t)node * HC + v0];
    xv[0] = bf2f(ux.x); xv[1] = bf2f(ux.y); xv[2] = bf2f(ux.z); xv[3] = bf2f(ux.w);
  }
  float bg[4];
  *(float4*)bg = *(const float4*)&b_gat[v0];
  float s1, s2;
  ushort4 ov;
  {
    float v0f = fmaf((float)agg01.x, inv, bg[0]) + xv[0];
    float v1f = fmaf((float)agg01.y, inv, bg[1]) + xv[1];
    float v2f = fmaf((float)agg23.x, inv, bg[2]) + xv[2];
    float v3f = fmaf((float)agg23.y, inv, bg[3]) + xv[3];
    s1 = v0f + v1f + v2f + v3f;
    s2 = v0f * v0f + v1f * v1f + v2f * v2f + v3f * v3f;
    ov.x = f2bf(v0f); ov.y = f2bf(v1f); ov.z = f2bf(v2f); ov.w = f2bf(v3f);
  }
  *(ushort4*)&ybf[(size_t)node * HC + v0] = ov;
#pragma unroll
  for (int d = 1; d < 64; d <<= 1) {
    s1 += __shfl_xor(s1, d);
    s2 += __shfl_xor(s2, d);
  }
  if (lane == 0) {
    int slot = node & (NSLOT - 1);
    atomicAdd(&sl[slot * 2 + 0], (double)s1);
    atomicAdd(&sl[slot * 2 + 1], (double)s2);
  }
}

// ============ merged LN1-finalize + W2T scale + bias fold ============
__global__ __launch_bounds__(256) void w2fold(
    const double* __restrict__ sl, const float* __restrict__ g1,
    const float* __restrict__ be1, u16* __restrict__ W2T,
    const float* __restrict__ b2, const float* __restrict__ W2,
    float* __restrict__ bias2p, double cnt)
{
  __shared__ double red[256][2];
  const int tid = threadIdx.x;
  double s1 = 0.0, s2 = 0.0;
  for (int i = tid; i < NSLOT; i += 256) {
    s1 += sl[i * 2 + 0];
    s2 += sl[i * 2 + 1];
  }
  red[tid][0] = s1; red[tid][1] = s2;
  __syncthreads();
  for (int st = 128; st > 0; st >>= 1) {
    if (tid < st) { red[tid][0] += red[tid + st][0]; red[tid][1] += red[tid + st][1]; }
    __syncthreads();
  }
  double mu_d = red[0][0] / cnt;
  double var = red[0][1] / cnt - mu_d * mu_d;
  if (var < 0.0) var = 0.0;
  const float sc = (float)(1.0 / (sqrt(var) + (double)LN_EPS));
  const float mu = (float)mu_d;
  const int bx = blockIdx.x;
  if (bx < 128) {
    const int i = bx * 256 + tid;
    const int kb = (i & 31) << 3;
    bf16x8 v = *(bf16x8*)&W2T[(size_t)i * 8];
    bf16x8 w;
#pragma unroll
    for (int j = 0; j < 8; ++j)
      w[j] = (short)f2bf(bf2f((u16)v[j]) * (sc * g1[kb + j]));
    *(bf16x8*)&W2T[(size_t)i * 8] = w;
  } else {
    const int n = (bx - 128) * 256 + tid;
    if (n < DHID) {
      float s = b2[n];
      for (int k = 0; k < HC; ++k) {
        float B1k = be1[k] - mu * sc * g1[k];
        s = fmaf(B1k, W2[(size_t)k * DHID + n], s);
      }
      bias2p[n] = s;
    }
  }
}

// ============ merged LN3-finalize + apply in place on d_out ============
__global__ __launch_bounds__(256) void ln_apply(
    const double* __restrict__ sl, const float* __restrict__ g3,
    const float* __restrict__ be3, float* __restrict__ z,
    long total4, double cnt)
{
  __shared__ double red[256][2];
  const int tid = threadIdx.x;
  double s1 = 0.0, s2 = 0.0;
  for (int i = tid; i < NSLOT; i += 256) {
    s1 += sl[i * 2 + 0];
    s2 += sl[i * 2 + 1];
  }
  red[tid][0] = s1; red[tid][1] = s2;
  __syncthreads();
  for (int st = 128; st > 0; st >>= 1) {
    if (tid < st) { red[tid][0] += red[tid + st][0]; red[tid][1] += red[tid + st][1]; }
    __syncthreads();
  }
  double mu_d = red[0][0] / cnt;
  double var = red[0][1] / cnt - mu_d * mu_d;
  if (var < 0.0) var = 0.0;
  const float sc = (float)(1.0 / (sqrt(var) + (double)LN_EPS));
  const float mu = (float)mu_d;
  for (long i = blockIdx.x * (long)blockDim.x + tid; i < total4;
       i += (long)gridDim.x * blockDim.x) {
    int c0 = (int)((i << 2) & (HC - 1));
    float4 v = ((float4*)z)[i];
    float4 gv = *(const float4*)&g3[c0];
    float4 bv = *(const float4*)&be3[c0];
    v.x = fmaf(v.x - mu, sc * gv.x, bv.x);
    v.y = fmaf(v.y - mu, sc * gv.y, bv.y);
    v.z = fmaf(v.z - mu, sc * gv.z, bv.z);
    v.w = fmaf(v.w - mu, sc * gv.w, bv.w);
    ((float4*)z)[i] = v;
  }
}

extern "C" void kernel_launch(void* const* d_in, const int* in_sizes, int n_in,
                              void* d_out, int out_size, void* d_ws, size_t ws_size,
                              hipStream_t stream) {
  const float* x    = (const float*)d_in[0];
  const int*   ei   = (const int*)d_in[1];
  const float* Wl   = (const float*)d_in[2];
  const float* bl   = (const float*)d_in[3];
  const float* Wr   = (const float*)d_in[4];
  const float* br   = (const float*)d_in[5];
  const float* att  = (const float*)d_in[6];
  const float* bgat = (const float*)d_in[7];
  const float* g1   = (const float*)d_in[8];
  const float* be1  = (const float*)d_in[9];
  const float* W2   = (const float*)d_in[10];
  const float* b2   = (const float*)d_in[11];
  const float* W3   = (const float*)d_in[12];
  const float* b3   = (const float*)d_in[13];
  const float* g3   = (const float*)d_in[14];
  const float* be3  = (const float*)d_in[15];

  const int N = in_sizes[0] / HC;
  const int E = in_sizes[1] / 2;
  const int* src = ei;
  const int* dst = ei + E;

  char* ws = (char*)d_ws;
  size_t o = 0;
  double* sl1 = (double*)(ws + o); o += (size_t)NSLOT * 16;
  double* sl3 = (double*)(ws + o); o += (size_t)NSLOT * 16;
  float* biascat = (float*)(ws + o); o += 512 * 4;
  float* bias2p = (float*)(ws + o); o += DHID * 4;
  u16* WT1 = (u16*)(ws + o); o += (size_t)512 * HC * 2;        // [WlT;WrT]: [512][256]
  u16* W2T = (u16*)(ws + o); o += (size_t)DHID * HC * 2;       // [1024][256]
  u16* W3T = (u16*)(ws + o); o += (size_t)HC * DHID * 2;       // [256][1024]
  int* deg = (int*)(ws + o); o += (size_t)N * 4;
  int* cur = (int*)(ws + o); o += (size_t)N * 4;               // contiguous with deg
  int* off = (int*)(ws + o); o += (size_t)(N + 1) * 4; o = (o + 15) & ~(size_t)15;
  int* csr = (int*)(ws + o); o += (size_t)E * 4; o = (o + 15) & ~(size_t)15;
  u16* xlr = (u16*)(ws + o); o += (size_t)N * 512 * 2;         // [N][512] f16 = xl | xr
  u16* h2m = (u16*)(ws + o); o += (size_t)N * DHID * 2;

  u16* ybf = (u16*)d_out;                     // y bf16: first half of d_out
  u16* xb  = (u16*)d_out + (size_t)N * HC;    // x bf16: second half of d_out
  float* z = (float*)d_out;                   // GEMM3's z overwrites everything later

  hipMemsetAsync(sl1, 0, (size_t)NSLOT * 32, stream);          // sl1 + sl3
  hipMemsetAsync(deg, 0, (size_t)N * 8, stream);               // deg + cur
  hipMemcpyAsync(biascat, bl, 256 * 4, hipMemcpyDeviceToDevice, stream);
  hipMemcpyAsync(biascat + 256, br, 256 * 4, hipMemcpyDeviceToDevice, stream);

  dim3 blk(256);
  const int mb = (N + 255) / 256;
  const int degBlocks = (E + 255) / 256;
  const int fillBlocks = (E + 511) / 512;
  const int g1Blocks = mb * 4;                 // GEMM1 grid (mb x 4 flattened)

  // merged pre-stage: xcvt (2048) | weight transposes (640) | deg_count
  pre_stage<<<2688 + degBlocks, blk, 0, stream>>>(
      x, xb, (long)N * HC / 8, Wl, Wr, W2, W3, WT1, W2T, W3T, dst, deg, E);

  scan_k<<<1, 1024, 0, stream>>>(deg, off, N);

  // GEMM1 (xlr = xb @ [Wl|Wr] + [bl|br], f16 out) fused with fill_csr
  gemm_mfma<false, 2, true><<<g1Blocks + fillBlocks, 512, 0, stream>>>(
      xb, WT1, biascat, xlr, nullptr, N, HC, 512, mb,
      src, dst, off, cur, csr, E, g1Blocks);

  // fused GATv2 + residual + LN1 partial stats
  gat_agg<<<(N + 3) / 4, blk, 0, stream>>>(xlr, xb, off, csr, att, bgat, ybf, sl1, N);

  // merged: LN1 finalize + W2T row-scale + bias2' fold
  w2fold<<<132, blk, 0, stream>>>(sl1, g1, be1, W2T, b2, W2, bias2p, (double)N * HC);

  // GEMM2: h2 = relu(ybf @ W2T' + bias2')  (bf16 out [N][1024])
  gemm_mfma<true, 1, false><<<dim3(mb, 8), 512, 0, stream>>>(
      ybf, W2T, bias2p, h2m, nullptr, N, HC, DHID, mb,
      nullptr, nullptr, nullptr, nullptr, nullptr, 0, 0);

  // GEMM3: z = h2 @ W3 + b3  (f32 out to d_out) + LN3 partial stats
  gemm_mfma<false, 0, false><<<dim3(mb, 2), 512, 0, stream>>>(
      h2m, W3T, b3, z, sl3, N, DHID, HC, mb,
      nullptr, nullptr, nullptr, nullptr, nullptr, 0, 0);

  // merged: LN3 finalize + apply in place
  ln_apply<<<2048, blk, 0, stream>>>(sl3, g3, be3, z, (long)N * HC / 4, (double)N * HC);
}

// Round 18
// 440.341 us; speedup vs baseline: 1.1324x; 1.0161x over previous
//
#include <hip/hip_runtime.h>
#include <hip/hip_bf16.h>

#define HC 256      // H*C == IN
#define DHID 1024
#define LN_EPS 1e-5f
#define NSLOT 1024  // distributed LN-stat accumulator slots (pairs of doubles)

typedef unsigned short u16;
typedef unsigned int u32;
typedef __attribute__((ext_vector_type(8))) short bf16x8;   // 8 bf16 = 4 VGPRs
typedef __attribute__((ext_vector_type(4))) float f32x4;
typedef _Float16 __attribute__((ext_vector_type(2))) h2;    // packed half pair

__device__ __forceinline__ float bf2f(u16 u) {
  union { u32 i; float f; } v; v.i = ((u32)u) << 16; return v.f;
}
__device__ __forceinline__ u16 f2bf(float f) {
  union { float f; u32 i; } v; v.f = f;
  u32 r = v.i + 0x7fffu + ((v.i >> 16) & 1u);
  return (u16)(r >> 16);
}
__device__ __forceinline__ u16 f2h(float f) {
  union { _Float16 h; u16 u; } v; v.h = (_Float16)f; return v.u;
}
__device__ __forceinline__ float dot2(h2 a, h2 b, float c) {
  return __builtin_amdgcn_fdot2(a, b, c, false);
}
__device__ __forceinline__ float fexp2(float x) {   // raw v_exp_f32: 2^x
  float r; asm("v_exp_f32 %0, %1" : "=v"(r) : "v"(x)); return r;
}
// async global->LDS 16B: per-lane global src, wave-uniform LDS base (+lane*16 in HW)
__device__ __forceinline__ void gload16(const u16* g, u16* ldsbase, int byteoff) {
  __builtin_amdgcn_global_load_lds(
      (const __attribute__((address_space(1))) void*)g,
      (__attribute__((address_space(3))) void*)((char*)ldsbase + byteoff),
      16, 0, 0);
}

// ================= MFMA GEMM (BM=256): out = op(A @ B^T_rowmajor + bias) =================
// BM=256 x BN=128 tile, BK=64, 512 threads = 8 waves (4 row x 2 col of 64x64).
// SINGLE-buffered 48KB LDS, launch_bounds(512,4) (R14/R16-proven best for
// GEMM1/2, whose grids are >1500 blocks). Pipelining regressed 3x (R4/R13/R15).
// XOR-16B swizzle, linear LDS, gload_lds staging.
// OMODE: 1 = bf16 out, 2 = f16 out. FUSE: tail blocks run fill_csr.
// C/D map (m89): col=lane&15, row=(lane>>4)*4+reg.
template<bool RELU, int OMODE, bool FUSE>
__global__ __launch_bounds__(512, 4) void gemm_mfma(
    const u16* __restrict__ Ab, const u16* __restrict__ BT,
    const float* __restrict__ bias,
    void* __restrict__ outp, double* __restrict__ sl,
    int M, int K, int NB, int mb,
    const int* __restrict__ srcE, const int* __restrict__ dstE,
    const int* __restrict__ offc, int* __restrict__ cur,
    int* __restrict__ csr, int E, int gemmBlocks)
{
  __shared__ __align__(16) u16 Asm[256 * 64];   // 32 KB
  __shared__ __align__(16) u16 Bsm[128 * 64];   // 16 KB
  int bxl, byl;
  if (FUSE) {
    if ((int)blockIdx.x >= gemmBlocks) {        // fill_csr blocks
      int i = ((int)blockIdx.x - gemmBlocks) * 512 + threadIdx.x;
      if (i < E) {
        int d = dstE[i];
        int pos = offc[d] + atomicAdd(&cur[d], 1);
        csr[pos] = srcE[i] << 10;               // pre-shifted byte offset
      }
      return;
    }
    bxl = blockIdx.x % mb; byl = blockIdx.x / mb;
  } else {
    bxl = blockIdx.x; byl = blockIdx.y;
  }
  const int tid = threadIdx.x;
  const int wid = tid >> 6, lane = tid & 63;
  const int rowBase = bxl * 256;
  const int colBase = byl * 128;
  const int wr = (wid >> 1) * 64, wc = (wid & 1) * 64;
  const int ccol = lane & 15, g = lane >> 4;
  f32x4 acc[4][4] = {};
  const int nt = K >> 6;

  for (int t = 0; t < nt; ++t) {
    const int k0 = t << 6;
#pragma unroll
    for (int s = 0; s < 4; ++s) {     // A 256x64 (2048 chunks / 512 thr)
      const int L = s * 512 + tid;
      const int r = L >> 3;
      const int gc = ((L & 7) ^ (r & 7)) << 3;
      int gr = rowBase + r; gr = gr < M ? gr : M - 1;
      const int lb = __builtin_amdgcn_readfirstlane(s * 8192 + wid * 1024);
      gload16(&Ab[(size_t)gr * K + k0 + gc], Asm, lb);
    }
#pragma unroll
    for (int s = 0; s < 2; ++s) {     // B^T 128x64
      const int L = s * 512 + tid;
      const int r = L >> 3;
      const int gc = ((L & 7) ^ (r & 7)) << 3;
      const int lb = __builtin_amdgcn_readfirstlane(s * 8192 + wid * 1024);
      gload16(&BT[(size_t)(colBase + r) * K + k0 + gc], Bsm, lb);
    }
    __syncthreads();
#pragma unroll
    for (int kk = 0; kk < 2; ++kk) {
      bf16x8 af[4], bfr[4];
      const int q = kk * 4 + g;
#pragma unroll
      for (int mr = 0; mr < 4; ++mr) {
        const int row = wr + mr * 16 + ccol;
        af[mr] = *(const bf16x8*)&Asm[(row << 6) + ((q ^ (row & 7)) << 3)];
      }
#pragma unroll
      for (int nc = 0; nc < 4; ++nc) {
        const int row = wc + nc * 16 + ccol;
        bfr[nc] = *(const bf16x8*)&Bsm[(row << 6) + ((q ^ (row & 7)) << 3)];
      }
#pragma unroll
      for (int mr = 0; mr < 4; ++mr)
#pragma unroll
        for (int nc = 0; nc < 4; ++nc)
          acc[mr][nc] = __builtin_amdgcn_mfma_f32_16x16x32_bf16(af[mr], bfr[nc], acc[mr][nc], 0, 0, 0);
    }
    __syncthreads();
  }

  // ---- epilogue ----
  u16* ob = (u16*)outp;
  const int crow = g * 4;
#pragma unroll
  for (int mr = 0; mr < 4; ++mr) {
#pragma unroll
    for (int nc = 0; nc < 4; ++nc) {
      const int gc = colBase + wc + nc * 16 + ccol;
      const float bv = bias[gc];
#pragma unroll
      for (int j = 0; j < 4; ++j) {
        const int gr = rowBase + wr + mr * 16 + crow + j;
        if (gr < M) {
          float v = acc[mr][nc][j] + bv;
          if (RELU) v = fmaxf(v, 0.f);
          if (OMODE == 1) ob[(size_t)gr * NB + gc] = f2bf(v);
          else            ob[(size_t)gr * NB + gc] = f2h(v);
        }
      }
    }
  }
}

// ================= MFMA GEMM small-tile (BM=128) for GEMM3 =================
// GEMM3 has K=1024 (nt=16, deepest serial chain) but at BM=256 its grid is
// only 392 blocks (~1.5 blocks/CU) -> nothing hides the per-step vmcnt drain.
// BM=128 x BN=128, 256 threads (2x2 waves of 64x64), 32KB LDS, lb(256,4):
// grid 782, ~3-4 co-resident blocks/CU mutually hide the chain (R9-proven body).
// f32 out + LN stats.
__global__ __launch_bounds__(256, 4) void gemm_mfma_s(
    const u16* __restrict__ Ab, const u16* __restrict__ BT,
    const float* __restrict__ bias,
    float* __restrict__ of, double* __restrict__ sl,
    int M, int K, int NB)
{
  __shared__ __align__(16) u16 Asm[128 * 64];   // 16 KB
  __shared__ __align__(16) u16 Bsm[128 * 64];   // 16 KB
  const int tid = threadIdx.x;
  const int wid = tid >> 6, lane = tid & 63;
  const int rowBase = blockIdx.x * 128;
  const int colBase = blockIdx.y * 128;
  const int wr = (wid >> 1) * 64, wc = (wid & 1) * 64;
  const int ccol = lane & 15, g = lane >> 4;
  f32x4 acc[4][4] = {};
  const int nt = K >> 6;

  for (int t = 0; t < nt; ++t) {
    const int k0 = t << 6;
#pragma unroll
    for (int s = 0; s < 4; ++s) {     // A 128x64 (1024 chunks / 256 thr)
      const int L = s * 256 + tid;
      const int r = L >> 3;
      const int gc = ((L & 7) ^ (r & 7)) << 3;
      int gr = rowBase + r; gr = gr < M ? gr : M - 1;
      const int lb = __builtin_amdgcn_readfirstlane(s * 4096 + wid * 1024);
      gload16(&Ab[(size_t)gr * K + k0 + gc], Asm, lb);
    }
#pragma unroll
    for (int s = 0; s < 4; ++s) {     // B^T 128x64
      const int L = s * 256 + tid;
      const int r = L >> 3;
      const int gc = ((L & 7) ^ (r & 7)) << 3;
      const int lb = __builtin_amdgcn_readfirstlane(s * 4096 + wid * 1024);
      gload16(&BT[(size_t)(colBase + r) * K + k0 + gc], Bsm, lb);
    }
    __syncthreads();
#pragma unroll
    for (int kk = 0; kk < 2; ++kk) {
      bf16x8 af[4], bfr[4];
      const int q = kk * 4 + g;
#pragma unroll
      for (int mr = 0; mr < 4; ++mr) {
        const int row = wr + mr * 16 + ccol;
        af[mr] = *(const bf16x8*)&Asm[(row << 6) + ((q ^ (row & 7)) << 3)];
      }
#pragma unroll
      for (int nc = 0; nc < 4; ++nc) {
        const int row = wc + nc * 16 + ccol;
        bfr[nc] = *(const bf16x8*)&Bsm[(row << 6) + ((q ^ (row & 7)) << 3)];
      }
#pragma unroll
      for (int mr = 0; mr < 4; ++mr)
#pragma unroll
        for (int nc = 0; nc < 4; ++nc)
          acc[mr][nc] = __builtin_amdgcn_mfma_f32_16x16x32_bf16(af[mr], bfr[nc], acc[mr][nc], 0, 0, 0);
    }
    __syncthreads();
  }

  // ---- epilogue: f32 out + LN stats ----
  const int crow = g * 4;
  float s1 = 0.f, s2 = 0.f;
#pragma unroll
  for (int mr = 0; mr < 4; ++mr) {
#pragma unroll
    for (int nc = 0; nc < 4; ++nc) {
      const int gc = colBase + wc + nc * 16 + ccol;
      const float bv = bias[gc];
#pragma unroll
      for (int j = 0; j < 4; ++j) {
        const int gr = rowBase + wr + mr * 16 + crow + j;
        if (gr < M) {
          float v = acc[mr][nc][j] + bv;
          of[(size_t)gr * NB + gc] = v;
          s1 += v; s2 += v * v;
        }
      }
    }
  }
#pragma unroll
  for (int d = 1; d < 64; d <<= 1) {
    s1 += __shfl_xor(s1, d);
    s2 += __shfl_xor(s2, d);
  }
  if (lane == 0) {
    int slot = ((blockIdx.x + blockIdx.y * 397) * 4 + wid) & (NSLOT - 1);
    atomicAdd(&sl[slot * 2 + 0], (double)s1);
    atomicAdd(&sl[slot * 2 + 1], (double)s2);
  }
}

// ============ merged pre-stage: xcvt | transpose_all | deg_count ============
__global__ __launch_bounds__(256) void pre_stage(
    const float* __restrict__ x, u16* __restrict__ xb, long n8,
    const float* __restrict__ Wl, const float* __restrict__ Wr,
    const float* __restrict__ W2, const float* __restrict__ W3,
    u16* __restrict__ WT1, u16* __restrict__ W2T, u16* __restrict__ W3T,
    const int* __restrict__ dst, int* __restrict__ deg, int E)
{
  __shared__ float T[32][33];
  const int bx = blockIdx.x;
  if (bx < 2048) {
    for (long i = (long)bx * 256 + threadIdx.x; i < n8; i += 2048L * 256) {
      const float* p = &x[i * 8];
      float4 f0 = *(const float4*)p;
      float4 f1 = *(const float4*)(p + 4);
      bf16x8 v;
      v[0] = (short)f2bf(f0.x); v[1] = (short)f2bf(f0.y);
      v[2] = (short)f2bf(f0.z); v[3] = (short)f2bf(f0.w);
      v[4] = (short)f2bf(f1.x); v[5] = (short)f2bf(f1.y);
      v[6] = (short)f2bf(f1.z); v[7] = (short)f2bf(f1.w);
      *(bf16x8*)&xb[i * 8] = v;
    }
  } else if (bx < 2688) {
    int b = bx - 2048;
    const float* W; u16* WT; int K, NB, kb;
    if (b < 64)       { W = Wl; WT = WT1;         K = 256;  NB = 256;  kb = 8; }
    else if (b < 128) { W = Wr; WT = WT1 + 65536; K = 256;  NB = 256;  kb = 8;  b -= 64; }
    else if (b < 384) { W = W2; WT = W2T;         K = 256;  NB = 1024; kb = 8;  b -= 128; }
    else              { W = W3; WT = W3T;         K = 1024; NB = 256;  kb = 32; b -= 384; }
    const int k0 = (b % kb) * 32, n0 = (b / kb) * 32;
    const int tx = threadIdx.x & 31, ty = threadIdx.x >> 5;   // 32 x 8
#pragma unroll
    for (int i = 0; i < 32; i += 8)
      T[ty + i][tx] = W[(size_t)(k0 + ty + i) * NB + n0 + tx];
    __syncthreads();
#pragma unroll
    for (int i = 0; i < 32; i += 8)
      WT[(size_t)(n0 + ty + i) * K + k0 + tx] = f2bf(T[tx][ty + i]);
  } else {
    int i = (bx - 2688) * 256 + threadIdx.x;
    if (i < E) atomicAdd(&deg[dst[i]], 1);
  }
}

// ---------------- CSR build: run-per-thread exclusive scan ----------------
__global__ __launch_bounds__(1024) void scan_k(const int* __restrict__ deg, int* __restrict__ off, int n) {
  __shared__ int wsum[16];
  const int tid = threadIdx.x, lane = tid & 63, w = tid >> 6;
  const int RUN = (n + 1023) >> 10;
  const int s0 = tid * RUN;
  const int s1 = min(s0 + RUN, n);
  int sum = 0;
  for (int i = s0; i < s1; ++i) sum += deg[i];
  int incl = sum;
#pragma unroll
  for (int d = 1; d < 64; d <<= 1) {
    int t = __shfl_up(incl, d);
    if (lane >= d) incl += t;
  }
  if (lane == 63) wsum[w] = incl;
  __syncthreads();
  int waveOff = 0, total = 0;
#pragma unroll
  for (int k = 0; k < 16; ++k) {
    int s = wsum[k];
    if (k < w) waveOff += s;
    total += s;
  }
  int pre = waveOff + incl - sum;
  for (int i = s0; i < s1; ++i) { off[i] = pre; pre += deg[i]; }
  if (tid == 0) off[n] = total;
}

// ---------------- fused GATv2 edge-softmax-aggregate: one wave per node ----------------
// xlr f16 [N][512] (xl | xr). att pre-scaled by log2e -> p = v_exp_f32(part - m0).
// csr entries are pre-shifted byte offsets. 8-edge chunks. Residual from xb (bf16).
__global__ __launch_bounds__(256) void gat_agg(
    const u16* __restrict__ xlr, const u16* __restrict__ xb,
    const int* __restrict__ off, const int* __restrict__ csr,
    const float* __restrict__ att, const float* __restrict__ b_gat,
    u16* __restrict__ ybf, double* __restrict__ sl, int N)
{
  const int lane = threadIdx.x & 63;
  const int node = blockIdx.x * 4 + (threadIdx.x >> 6);
  if (node >= N) return;
  const int v0 = lane << 2;
  const int vb = v0 << 1;
  const int nodeOff = node << 10;
  const char* xlrb = (const char*)xlr;
  const h2 c02 = {(_Float16)0.2f, (_Float16)0.2f};
  h2 att01, att23;
  {
    const float L2E = 1.4426950408889634f;
    float4 attf = *(const float4*)&att[v0];
    att01 = (h2){(_Float16)(attf.x * L2E), (_Float16)(attf.y * L2E)};
    att23 = (h2){(_Float16)(attf.z * L2E), (_Float16)(attf.w * L2E)};
  }
  h2 xr01, xr23;
  {
    uint2 ux = *(const uint2*)(xlrb + nodeOff + 512 + vb);
    xr01 = __builtin_bit_cast(h2, ux.x);
    xr23 = __builtin_bit_cast(h2, ux.y);
  }
  // self-loop: reference logit m0 (log2 domain), p_self = 1
  float m0, d_run = 1.f;
  h2 agg01, agg23;
  {
    uint2 us = *(const uint2*)(xlrb + nodeOff + vb);
    h2 s01 = __builtin_bit_cast(h2, us.x);
    h2 s23 = __builtin_bit_cast(h2, us.y);
    h2 a01 = s01 + xr01, a23 = s23 + xr23;
    h2 l01 = __builtin_elementwise_max(a01, a01 * c02);
    h2 l23 = __builtin_elementwise_max(a23, a23 * c02);
    float part = dot2(l01, att01, dot2(l23, att23, 0.f));
    part += __shfl_xor(part, 1);
    part += __shfl_xor(part, 2);
    part += __shfl_xor(part, 4);
    m0 = part;
    agg01 = s01; agg23 = s23;
  }
  const int beg = off[node];
  const int cntE = off[node + 1] - beg;
  for (int e0 = 0; e0 < cntE; e0 += 8) {
    const int nb = cntE - e0;   // valid this chunk: min(nb, 8)
    int jj[8];
#pragma unroll
    for (int t = 0; t < 8; ++t)
      jj[t] = (t < nb) ? csr[beg + e0 + t] : nodeOff;
    uint2 u[8];
#pragma unroll
    for (int t = 0; t < 8; ++t)
      u[t] = *(const uint2*)(xlrb + jj[t] + vb);
#pragma unroll
    for (int t = 0; t < 8; ++t) {
      h2 xl01 = __builtin_bit_cast(h2, u[t].x);
      h2 xl23 = __builtin_bit_cast(h2, u[t].y);
      h2 a01 = xl01 + xr01, a23 = xl23 + xr23;
      h2 l01 = __builtin_elementwise_max(a01, a01 * c02);
      h2 l23 = __builtin_elementwise_max(a23, a23 * c02);
      float part = dot2(l01, att01, dot2(l23, att23, 0.f));
      part += __shfl_xor(part, 1);
      part += __shfl_xor(part, 2);
      part += __shfl_xor(part, 4);
      float p = (t < nb) ? fexp2(part - m0) : 0.f;
      d_run += p;
      _Float16 ph = (_Float16)p;
      h2 pv = {ph, ph};
      agg01 += pv * xl01;    // v_pk_fma_f16
      agg23 += pv * xl23;
    }
  }
  const float inv = 1.f / d_run;
  float xv[4];
  {
    ushort4 ux = *(const ushort4*)&xb[(size_t)node * HC + v0];
    xv[0] = bf2f(ux.x); xv[1] = bf2f(ux.y); xv[2] = bf2f(ux.z); xv[3] = bf2f(ux.w);
  }
  float bg[4];
  *(float4*)bg = *(const float4*)&b_gat[v0];
  float s1, s2;
  ushort4 ov;
  {
    float v0f = fmaf((float)agg01.x, inv, bg[0]) + xv[0];
    float v1f = fmaf((float)agg01.y, inv, bg[1]) + xv[1];
    float v2f = fmaf((float)agg23.x, inv, bg[2]) + xv[2];
    float v3f = fmaf((float)agg23.y, inv, bg[3]) + xv[3];
    s1 = v0f + v1f + v2f + v3f;
    s2 = v0f * v0f + v1f * v1f + v2f * v2f + v3f * v3f;
    ov.x = f2bf(v0f); ov.y = f2bf(v1f); ov.z = f2bf(v2f); ov.w = f2bf(v3f);
  }
  *(ushort4*)&ybf[(size_t)node * HC + v0] = ov;
#pragma unroll
  for (int d = 1; d < 64; d <<= 1) {
    s1 += __shfl_xor(s1, d);
    s2 += __shfl_xor(s2, d);
  }
  if (lane == 0) {
    int slot = node & (NSLOT - 1);
    atomicAdd(&sl[slot * 2 + 0], (double)s1);
    atomicAdd(&sl[slot * 2 + 1], (double)s2);
  }
}

// ============ merged LN1-finalize + W2T scale + bias fold ============
__global__ __launch_bounds__(256) void w2fold(
    const double* __restrict__ sl, const float* __restrict__ g1,
    const float* __restrict__ be1, u16* __restrict__ W2T,
    const float* __restrict__ b2, const float* __restrict__ W2,
    float* __restrict__ bias2p, double cnt)
{
  __shared__ double red[256][2];
  const int tid = threadIdx.x;
  double s1 = 0.0, s2 = 0.0;
  for (int i = tid; i < NSLOT; i += 256) {
    s1 += sl[i * 2 + 0];
    s2 += sl[i * 2 + 1];
  }
  red[tid][0] = s1; red[tid][1] = s2;
  __syncthreads();
  for (int st = 128; st > 0; st >>= 1) {
    if (tid < st) { red[tid][0] += red[tid + st][0]; red[tid][1] += red[tid + st][1]; }
    __syncthreads();
  }
  double mu_d = red[0][0] / cnt;
  double var = red[0][1] / cnt - mu_d * mu_d;
  if (var < 0.0) var = 0.0;
  const float sc = (float)(1.0 / (sqrt(var) + (double)LN_EPS));
  const float mu = (float)mu_d;
  const int bx = blockIdx.x;
  if (bx < 128) {
    const int i = bx * 256 + tid;
    const int kb = (i & 31) << 3;
    bf16x8 v = *(bf16x8*)&W2T[(size_t)i * 8];
    bf16x8 w;
#pragma unroll
    for (int j = 0; j < 8; ++j)
      w[j] = (short)f2bf(bf2f((u16)v[j]) * (sc * g1[kb + j]));
    *(bf16x8*)&W2T[(size_t)i * 8] = w;
  } else {
    const int n = (bx - 128) * 256 + tid;
    if (n < DHID) {
      float s = b2[n];
      for (int k = 0; k < HC; ++k) {
        float B1k = be1[k] - mu * sc * g1[k];
        s = fmaf(B1k, W2[(size_t)k * DHID + n], s);
      }
      bias2p[n] = s;
    }
  }
}

// ============ merged LN3-finalize + apply in place on d_out ============
__global__ __launch_bounds__(256) void ln_apply(
    const double* __restrict__ sl, const float* __restrict__ g3,
    const float* __restrict__ be3, float* __restrict__ z,
    long total4, double cnt)
{
  __shared__ double red[256][2];
  const int tid = threadIdx.x;
  double s1 = 0.0, s2 = 0.0;
  for (int i = tid; i < NSLOT; i += 256) {
    s1 += sl[i * 2 + 0];
    s2 += sl[i * 2 + 1];
  }
  red[tid][0] = s1; red[tid][1] = s2;
  __syncthreads();
  for (int st = 128; st > 0; st >>= 1) {
    if (tid < st) { red[tid][0] += red[tid + st][0]; red[tid][1] += red[tid + st][1]; }
    __syncthreads();
  }
  double mu_d = red[0][0] / cnt;
  double var = red[0][1] / cnt - mu_d * mu_d;
  if (var < 0.0) var = 0.0;
  const float sc = (float)(1.0 / (sqrt(var) + (double)LN_EPS));
  const float mu = (float)mu_d;
  for (long i = blockIdx.x * (long)blockDim.x + tid; i < total4;
       i += (long)gridDim.x * blockDim.x) {
    int c0 = (int)((i << 2) & (HC - 1));
    float4 v = ((float4*)z)[i];
    float4 gv = *(const float4*)&g3[c0];
    float4 bv = *(const float4*)&be3[c0];
    v.x = fmaf(v.x - mu, sc * gv.x, bv.x);
    v.y = fmaf(v.y - mu, sc * gv.y, bv.y);
    v.z = fmaf(v.z - mu, sc * gv.z, bv.z);
    v.w = fmaf(v.w - mu, sc * gv.w, bv.w);
    ((float4*)z)[i] = v;
  }
}

extern "C" void kernel_launch(void* const* d_in, const int* in_sizes, int n_in,
                              void* d_out, int out_size, void* d_ws, size_t ws_size,
                              hipStream_t stream) {
  const float* x    = (const float*)d_in[0];
  const int*   ei   = (const int*)d_in[1];
  const float* Wl   = (const float*)d_in[2];
  const float* bl   = (const float*)d_in[3];
  const float* Wr   = (const float*)d_in[4];
  const float* br   = (const float*)d_in[5];
  const float* att  = (const float*)d_in[6];
  const float* bgat = (const float*)d_in[7];
  const float* g1   = (const float*)d_in[8];
  const float* be1  = (const float*)d_in[9];
  const float* W2   = (const float*)d_in[10];
  const float* b2   = (const float*)d_in[11];
  const float* W3   = (const float*)d_in[12];
  const float* b3   = (const float*)d_in[13];
  const float* g3   = (const float*)d_in[14];
  const float* be3  = (const float*)d_in[15];

  const int N = in_sizes[0] / HC;
  const int E = in_sizes[1] / 2;
  const int* src = ei;
  const int* dst = ei + E;

  char* ws = (char*)d_ws;
  size_t o = 0;
  double* sl1 = (double*)(ws + o); o += (size_t)NSLOT * 16;
  double* sl3 = (double*)(ws + o); o += (size_t)NSLOT * 16;
  float* biascat = (float*)(ws + o); o += 512 * 4;
  float* bias2p = (float*)(ws + o); o += DHID * 4;
  u16* WT1 = (u16*)(ws + o); o += (size_t)512 * HC * 2;        // [WlT;WrT]: [512][256]
  u16* W2T = (u16*)(ws + o); o += (size_t)DHID * HC * 2;       // [1024][256]
  u16* W3T = (u16*)(ws + o); o += (size_t)HC * DHID * 2;       // [256][1024]
  int* deg = (int*)(ws + o); o += (size_t)N * 4;
  int* cur = (int*)(ws + o); o += (size_t)N * 4;               // contiguous with deg
  int* off = (int*)(ws + o); o += (size_t)(N + 1) * 4; o = (o + 15) & ~(size_t)15;
  int* csr = (int*)(ws + o); o += (size_t)E * 4; o = (o + 15) & ~(size_t)15;
  u16* xlr = (u16*)(ws + o); o += (size_t)N * 512 * 2;         // [N][512] f16 = xl | xr
  u16* h2m = (u16*)(ws + o); o += (size_t)N * DHID * 2;

  u16* ybf = (u16*)d_out;                     // y bf16: first half of d_out
  u16* xb  = (u16*)d_out + (size_t)N * HC;    // x bf16: second half of d_out
  float* z = (float*)d_out;                   // GEMM3's z overwrites everything later

  hipMemsetAsync(sl1, 0, (size_t)NSLOT * 32, stream);          // sl1 + sl3
  hipMemsetAsync(deg, 0, (size_t)N * 8, stream);               // deg + cur
  hipMemcpyAsync(biascat, bl, 256 * 4, hipMemcpyDeviceToDevice, stream);
  hipMemcpyAsync(biascat + 256, br, 256 * 4, hipMemcpyDeviceToDevice, stream);

  dim3 blk(256);
  const int mb = (N + 255) / 256;              // BM=256 grid rows (GEMM1/2)
  const int mbs = (N + 127) / 128;             // BM=128 grid rows (GEMM3)
  const int degBlocks = (E + 255) / 256;
  const int fillBlocks = (E + 511) / 512;
  const int g1Blocks = mb * 4;                 // GEMM1 grid (mb x 4 flattened)

  // merged pre-stage: xcvt (2048) | weight transposes (640) | deg_count
  pre_stage<<<2688 + degBlocks, blk, 0, stream>>>(
      x, xb, (long)N * HC / 8, Wl, Wr, W2, W3, WT1, W2T, W3T, dst, deg, E);

  scan_k<<<1, 1024, 0, stream>>>(deg, off, N);

  // GEMM1 (xlr = xb @ [Wl|Wr] + [bl|br], f16 out) fused with fill_csr
  gemm_mfma<false, 2, true><<<g1Blocks + fillBlocks, 512, 0, stream>>>(
      xb, WT1, biascat, xlr, nullptr, N, HC, 512, mb,
      src, dst, off, cur, csr, E, g1Blocks);

  // fused GATv2 + residual + LN1 partial stats
  gat_agg<<<(N + 3) / 4, blk, 0, stream>>>(xlr, xb, off, csr, att, bgat, ybf, sl1, N);

  // merged: LN1 finalize + W2T row-scale + bias2' fold
  w2fold<<<132, blk, 0, stream>>>(sl1, g1, be1, W2T, b2, W2, bias2p, (double)N * HC);

  // GEMM2: h2 = relu(ybf @ W2T' + bias2')  (bf16 out [N][1024])
  gemm_mfma<true, 1, false><<<dim3(mb, 8), 512, 0, stream>>>(
      ybf, W2T, bias2p, h2m, nullptr, N, HC, DHID, mb,
      nullptr, nullptr, nullptr, nullptr, nullptr, 0, 0);

  // GEMM3 (small-tile): z = h2 @ W3 + b3  (f32 out) + LN3 stats — 782 blocks
  gemm_mfma_s<<<dim3(mbs, 2), blk, 0, stream>>>(
      h2m, W3T, b3, z, sl3, N, DHID, HC);

  // merged: LN3 finalize + apply in place
  ln_apply<<<2048, blk, 0, stream>>>(sl3, g3, be3, z, (long)N * HC / 4, (double)N * HC);
}